// Round 4
// baseline (30083.118 us; speedup 1.0000x reference)
//
#include <hip/hip_runtime.h>

// BasicGRU persistent kernel for MI355X (gfx950) — round 4.
//
// Barrier-free dataflow pipeline. Every cross-wg element (h, h*r) is a single
// atomic u64 { low32 = tag (step id), high32 = packed bf16 hi/lo }. Consumers
// poll the data itself per 8-element chunk (wave-wide __all on tags) and run
// MFMA as chunks arrive. No flags, no barriers, no vmcnt drains -> the serial
// chain per step is just: h store -> visible -> r compute -> hr store ->
// visible -> u compute -> h store.
//
// Buffers double by step parity; WAR safety: h(t) visible => all reads of
// h(t-2)/hr(t-1) retired (transitively through the consumption chain), so
// overwriting the parity buffer is safe. Tags are full step numbers (no ABA).
//
// wg roles (4 batch groups x 16 rows; 64 wgs per group):
//   r-wg (cb<32):  r-gate cols [cb*16,+16): poll h(t-1), GEMM, hr store.
//   z-wg (cb>=32): z-gate cols 512+(cb-32)*16 in phase 1 (zt stays in reg),
//                  u cols (cb-32)*16: xu part early (x-only), then poll hr(t),
//                  h-part GEMM, h(t) store. split_x(t+1) hides under hr poll.
//
// ws: h2  u64[2][64][512] @ 0       (512 KiB)
//     hr2 u64[2][64][512] @ 524288  (512 KiB)   total 1 MiB, memset 0/launch.

#define TT 2048
#define DD 256
#define UU 512

typedef short bf16x8 __attribute__((ext_vector_type(8)));
typedef float f32x4 __attribute__((ext_vector_type(4)));
typedef unsigned int u32;
typedef unsigned long long u64;

#define H2_OFF 0
#define HR2_OFF 524288
#define WS_BYTES 1048576

__device__ inline unsigned short f2bf(float f) {
  unsigned u = __builtin_bit_cast(unsigned, f);
  u += 0x7FFFu + ((u >> 16) & 1u);  // round-nearest-even
  return (unsigned short)(u >> 16);
}
__device__ inline float bf2f(unsigned short b) {
  unsigned u = ((unsigned)b) << 16;
  return __builtin_bit_cast(float, u);
}
__device__ inline u64 ld_coh_u64(const u64* p) {
  return __hip_atomic_load(p, __ATOMIC_RELAXED, __HIP_MEMORY_SCOPE_AGENT);
}
__device__ inline void st_coh_u64(u64* p, u64 v) {
  __hip_atomic_store(p, v, __ATOMIC_RELAXED, __HIP_MEMORY_SCOPE_AGENT);
}

#define MFMA(A, B, C) __builtin_amdgcn_mfma_f32_16x16x32_bf16((A), (B), (C), 0, 0, 0)

__global__ __launch_bounds__(256, 1) void gru_persist(
    const float* __restrict__ x, const float* __restrict__ Wk,
    const float* __restrict__ Wrk, const float* __restrict__ brk,
    const float* __restrict__ Wu, const float* __restrict__ Wur,
    const float* __restrict__ bur, float* __restrict__ out,
    unsigned char* __restrict__ ws) {
  __shared__ float scratch[24576];  // 96 KiB: [0,1024) used, rest pins 1 wg/CU

  const int wg = blockIdx.x;
  const int bblk = wg & 3;          // batch group (16 rows)
  const int cb = wg >> 2;           // 0..63
  const bool zwg = (cb >= 32);
  const int tid = threadIdx.x;
  const int lane = tid & 63;
  const int wv = tid >> 6;
  const int kgrp = lane >> 4;
  const int c = lane & 15;

  const int P1C0 = cb * 16;                   // phase-1 col base in [0,1024)
  const int P2C0 = zwg ? (cb - 32) * 16 : 0;  // phase-2 u col base

  u64* h2 = (u64*)(ws + H2_OFF);    // [buf][row][k]
  u64* hr2 = (u64*)(ws + HR2_OFF);  // [buf][row][k]

  // ---- one-time: weight B-fragments -> registers (bf16 hi/lo split).
  // Wave wv owns K-chunks (wv + 4j)*32, j=0..5 (j<2 x-rows, j>=2 h-rows).
  bf16x8 w1hi[6], w1lo[6], w2hi[6], w2lo[6];
#pragma unroll
  for (int j = 0; j < 6; ++j) {
    const int kb = (wv + 4 * j) * 32 + kgrp * 8;
#pragma unroll
    for (int i = 0; i < 8; ++i) {
      const int k = kb + i;
      float v = (k < DD) ? Wk[(size_t)k * 1024 + P1C0 + c]
                         : Wrk[(size_t)(k - DD) * 1024 + P1C0 + c];
      unsigned short hb = f2bf(v);
      w1hi[j][i] = (short)hb;
      w1lo[j][i] = (short)f2bf(v - bf2f(hb));
      float v2 = 0.f;
      if (zwg)
        v2 = (k < DD) ? Wu[(size_t)k * UU + P2C0 + c]
                      : Wur[(size_t)(k - DD) * UU + P2C0 + c];
      unsigned short hb2 = f2bf(v2);
      w2hi[j][i] = (short)hb2;
      w2lo[j][i] = (short)f2bf(v2 - bf2f(hb2));
    }
  }

  const int bl = tid >> 4, cl = tid & 15;  // reduce-thread coords
  const int Bg = bblk * 16 + bl;
  const float b1 = brk[P1C0 + cl];
  const float b2 = zwg ? bur[P2C0 + cl] : 0.f;

  const int rowb = bblk * 16 + c;  // A-operand batch row for this lane

  // x fragments for the current step (shared by phase-1 and xu GEMMs).
  bf16x8 xhi[2], xlo[2];
  auto split_x = [&](int t) {
#pragma unroll
    for (int j = 0; j < 2; ++j) {
      const float* xr =
          x + ((size_t)rowb * TT + t) * DD + wv * 32 + j * 128 + kgrp * 8;
      f32x4 v0 = *(const f32x4*)(xr);
      f32x4 v1 = *(const f32x4*)(xr + 4);
#pragma unroll
      for (int i = 0; i < 4; ++i) {
        unsigned short hb = f2bf(v0[i]);
        xhi[j][i] = (short)hb;
        xlo[j][i] = (short)f2bf(v0[i] - bf2f(hb));
        unsigned short hb2 = f2bf(v1[i]);
        xhi[j][4 + i] = (short)hb2;
        xlo[j][4 + i] = (short)f2bf(v1[i] - bf2f(hb2));
      }
    }
  };

  // Poll one 8-element chunk (8 contiguous u64) until all tags == exp, then
  // unpack into bf16 hi/lo fragments. Wave-uniform loop (__all).
  auto poll_chunk = [&](const u64* p, u32 exp, bf16x8& AHI, bf16x8& ALO) {
    u64 q0, q1, q2, q3, q4, q5, q6, q7;
    for (;;) {
      q0 = ld_coh_u64(p + 0); q1 = ld_coh_u64(p + 1);
      q2 = ld_coh_u64(p + 2); q3 = ld_coh_u64(p + 3);
      q4 = ld_coh_u64(p + 4); q5 = ld_coh_u64(p + 5);
      q6 = ld_coh_u64(p + 6); q7 = ld_coh_u64(p + 7);
      int ok = ((u32)q0 == exp) & ((u32)q1 == exp) & ((u32)q2 == exp) &
               ((u32)q3 == exp) & ((u32)q4 == exp) & ((u32)q5 == exp) &
               ((u32)q6 == exp) & ((u32)q7 == exp);
      if (__all(ok)) break;
      __builtin_amdgcn_s_sleep(1);
    }
    u32 w;
    w = (u32)(q0 >> 32); AHI[0] = (short)(w >> 16); ALO[0] = (short)w;
    w = (u32)(q1 >> 32); AHI[1] = (short)(w >> 16); ALO[1] = (short)w;
    w = (u32)(q2 >> 32); AHI[2] = (short)(w >> 16); ALO[2] = (short)w;
    w = (u32)(q3 >> 32); AHI[3] = (short)(w >> 16); ALO[3] = (short)w;
    w = (u32)(q4 >> 32); AHI[4] = (short)(w >> 16); ALO[4] = (short)w;
    w = (u32)(q5 >> 32); AHI[5] = (short)(w >> 16); ALO[5] = (short)w;
    w = (u32)(q6 >> 32); AHI[6] = (short)(w >> 16); ALO[6] = (short)w;
    w = (u32)(q7 >> 32); AHI[7] = (short)(w >> 16); ALO[7] = (short)w;
  };

  split_x(0);

  for (int t = 0; t < TT; ++t) {
    const u32 exp_h = (u32)t;  // h(t-1) was stored with tag t (memset: tag 0)
    const u64* hrow = h2 + ((size_t)((t + 1) & 1) * 64 + rowb) * 512;

    // ================= phase 1: z/r = [x|h(t-1)] @ [Wk;Wrk] + brk (all wgs)
    f32x4 a0 = {0.f, 0.f, 0.f, 0.f}, a1 = {0.f, 0.f, 0.f, 0.f};
    a0 = MFMA(xhi[0], w1hi[0], a0);
    a0 = MFMA(xhi[0], w1lo[0], a0);
    a0 = MFMA(xlo[0], w1hi[0], a0);
    a1 = MFMA(xhi[1], w1hi[1], a1);
    a1 = MFMA(xhi[1], w1lo[1], a1);
    a1 = MFMA(xlo[1], w1hi[1], a1);
#pragma unroll
    for (int j = 2; j < 6; ++j) {
      const int kh = 32 * (wv + 4 * j - 8) + kgrp * 8;
      bf16x8 ahi, alo;
      poll_chunk(hrow + kh, exp_h, ahi, alo);
      if ((j & 1) == 0) {
        a0 = MFMA(ahi, w1hi[j], a0);
        a0 = MFMA(ahi, w1lo[j], a0);
        a0 = MFMA(alo, w1hi[j], a0);
      } else {
        a1 = MFMA(ahi, w1hi[j], a1);
        a1 = MFMA(ahi, w1lo[j], a1);
        a1 = MFMA(alo, w1hi[j], a1);
      }
    }
    {
      f32x4 acc = a0 + a1;
#pragma unroll
      for (int r = 0; r < 4; ++r)
        scratch[wv * 256 + (kgrp * 4 + r) * 16 + c] = acc[r];
    }
    __syncthreads();
    const float zsum = (scratch[tid] + scratch[256 + tid]) +
                       (scratch[512 + tid] + scratch[768 + tid]) + b1;
    const float s = 1.f / (1.f + __expf(-zsum));

    if (!zwg) {
      // r gate -> hr = h*r, tagged store. Own h is visible (wg-wide poll +
      // syncthreads above covered rows [bblk*16,+16) x k [0,512)).
      u64 hp = ld_coh_u64(h2 + ((size_t)((t + 1) & 1) * 64 + Bg) * 512 +
                          P1C0 + cl);
      u32 hw = (u32)(hp >> 32);
      float h = bf2f((unsigned short)(hw >> 16)) + bf2f((unsigned short)hw);
      float hrv = h * s;
      unsigned short hb = f2bf(hrv);
      unsigned short lb = f2bf(hrv - bf2f(hb));
      u64 pv = (((u64)(((u32)hb << 16) | lb)) << 32) | (u32)(t + 1);
      st_coh_u64(hr2 + ((size_t)(t & 1) * 64 + Bg) * 512 + P1C0 + cl, pv);
      // No extra sync needed: next-step scratch write is gated by polling
      // h(t), which needs z-wgs, which need ALL hr(t) incl. this wave's (whose
      // store dataflow-depends on this wave's scratch read).
      if (t + 1 < TT) split_x(t + 1);
    } else {
      const float zt = s;  // update gate stays in register
      // xu partial (x-only chunks of u-GEMM) — hr-independent, do it now.
      f32x4 u0 = {0.f, 0.f, 0.f, 0.f}, u1 = {0.f, 0.f, 0.f, 0.f};
      u0 = MFMA(xhi[0], w2hi[0], u0);
      u0 = MFMA(xhi[0], w2lo[0], u0);
      u0 = MFMA(xlo[0], w2hi[0], u0);
      u1 = MFMA(xhi[1], w2hi[1], u1);
      u1 = MFMA(xhi[1], w2lo[1], u1);
      u1 = MFMA(xlo[1], w2hi[1], u1);
      __syncthreads();  // all threads done reading z-scratch before u-write
      if (t + 1 < TT) split_x(t + 1);  // x(t+1) loads hide under hr poll

      // ================= phase 2: u h-part = hr(t) @ Wur
      const u32 exp_hr = (u32)(t + 1);
      const u64* hrrow = hr2 + ((size_t)(t & 1) * 64 + rowb) * 512;
#pragma unroll
      for (int j = 2; j < 6; ++j) {
        const int kh = 32 * (wv + 4 * j - 8) + kgrp * 8;
        bf16x8 ahi, alo;
        poll_chunk(hrrow + kh, exp_hr, ahi, alo);
        if ((j & 1) == 0) {
          u0 = MFMA(ahi, w2hi[j], u0);
          u0 = MFMA(ahi, w2lo[j], u0);
          u0 = MFMA(alo, w2hi[j], u0);
        } else {
          u1 = MFMA(ahi, w2hi[j], u1);
          u1 = MFMA(ahi, w2lo[j], u1);
          u1 = MFMA(alo, w2hi[j], u1);
        }
      }
      {
        f32x4 acc = u0 + u1;
#pragma unroll
        for (int r = 0; r < 4; ++r)
          scratch[wv * 256 + (kgrp * 4 + r) * 16 + c] = acc[r];
      }
      __syncthreads();
      const float usum = (scratch[tid] + scratch[256 + tid]) +
                         (scratch[512 + tid] + scratch[768 + tid]) + b2;
      const float e = __expf(2.f * usum);
      const float ht = 1.f - 2.f / (e + 1.f);  // tanh(usum)
      u64 hp2 = ld_coh_u64(h2 + ((size_t)((t + 1) & 1) * 64 + Bg) * 512 +
                           P2C0 + cl);
      u32 hw2 = (u32)(hp2 >> 32);
      float ho = bf2f((unsigned short)(hw2 >> 16)) + bf2f((unsigned short)hw2);
      float hn = ho + zt * (ht - ho);
      unsigned short hb = f2bf(hn);
      unsigned short lb = f2bf(hn - bf2f(hb));
      u64 pv = (((u64)(((u32)hb << 16) | lb)) << 32) | (u32)(t + 1);
      st_coh_u64(h2 + ((size_t)(t & 1) * 64 + Bg) * 512 + P2C0 + cl, pv);
      if (t == TT - 1) out[(size_t)Bg * UU + P2C0 + cl] = hn;
      // Next-step scratch write gated by polling h(t) (incl. own wave's
      // elements, whose stores dataflow-depend on this scratch read).
    }
  }
}

extern "C" void kernel_launch(void* const* d_in, const int* in_sizes, int n_in,
                              void* d_out, int out_size, void* d_ws,
                              size_t ws_size, hipStream_t stream) {
  (void)in_sizes; (void)n_in; (void)out_size; (void)ws_size;
  hipMemsetAsync(d_ws, 0, WS_BYTES, stream);  // h(-1)=0 with tag 0; hr tags 0
  gru_persist<<<dim3(256), dim3(256), 0, stream>>>(
      (const float*)d_in[0], (const float*)d_in[1], (const float*)d_in[2],
      (const float*)d_in[3], (const float*)d_in[4], (const float*)d_in[5],
      (const float*)d_in[6], (float*)d_out, (unsigned char*)d_ws);
}

// Round 5
// 20205.626 us; speedup vs baseline: 1.4888x; 1.4888x over previous
//
#include <hip/hip_runtime.h>

// BasicGRU persistent kernel for MI355X (gfx950) — round 5.
//
// 1-hop barrier-free dataflow with MANTISSA-TAGGED u32 elements:
//   u32 = (fp32_bits & ~0x7FF) | (step_tag & 0x7FF)
// The consumer's poll load IS the data load (no flag hop, no vmcnt drain on
// the critical path), at R3's exchange volume (u32/elem, half of R4's u64).
// Tag math (TT = 2048 = 2^11): h(t) stored with tag (t+1)&0x7FF, consumed at
// step t+1 expecting (t+1)&0x7FF; memset-0 = tag 0 = expected tag of h(-1)=0,
// so zero-init is already "ready" (no init kernel). hr(t) tag (t+1)&0x7FF,
// consumed same step; the t=2047 tag-0 aliases initial zeros but those were
// overwritten at t=1 (lockstep +-1 step) — benign.
// Value rel-err from tag bits: ~2^-12 (≪ 1.88e-2 threshold; h exchanged as
// tagged fp32, split to bf16 hi/lo on the consumer side by truncation).
//
// wg roles (4 batch groups x 16 rows; 64 wgs per group):
//   r-wg (cb<32):  r-gate cols [cb*16,+16): poll h(t-1), GEMM, hr store.
//   z-wg (cb>=32): z-gate cols 512+(cb-32)*16 in phase 1 (zt stays in reg),
//                  u cols (cb-32)*16: xu part early, then poll hr(t), h store.
//
// ws: h2  u32[2][64][512] @ 0       (256 KiB)
//     hr2 u32[2][64][512] @ 262144  (256 KiB)  total 512 KiB, memset 0.

#define TT 2048
#define DD 256
#define UU 512

typedef short bf16x8 __attribute__((ext_vector_type(8)));
typedef float f32x4 __attribute__((ext_vector_type(4)));
typedef unsigned int u32;

#define H2_OFF 0
#define HR2_OFF 262144
#define WS_BYTES 524288
#define TAGM 0x7FFu

__device__ inline unsigned short f2bf(float f) {
  unsigned u = __builtin_bit_cast(unsigned, f);
  u += 0x7FFFu + ((u >> 16) & 1u);  // round-nearest-even
  return (unsigned short)(u >> 16);
}
__device__ inline float bf2f(unsigned short b) {
  unsigned u = ((unsigned)b) << 16;
  return __builtin_bit_cast(float, u);
}
__device__ inline u32 ld_coh_u32(const u32* p) {
  return __hip_atomic_load(p, __ATOMIC_RELAXED, __HIP_MEMORY_SCOPE_AGENT);
}
__device__ inline void st_coh_u32(u32* p, u32 v) {
  __hip_atomic_store(p, v, __ATOMIC_RELAXED, __HIP_MEMORY_SCOPE_AGENT);
}
__device__ inline float untag(u32 q) {
  return __builtin_bit_cast(float, q & 0xFFFFF800u);
}

#define MFMA(A, B, C) __builtin_amdgcn_mfma_f32_16x16x32_bf16((A), (B), (C), 0, 0, 0)

__global__ __launch_bounds__(256, 1) void gru_persist(
    const float* __restrict__ x, const float* __restrict__ Wk,
    const float* __restrict__ Wrk, const float* __restrict__ brk,
    const float* __restrict__ Wu, const float* __restrict__ Wur,
    const float* __restrict__ bur, float* __restrict__ out,
    unsigned char* __restrict__ ws) {
  __shared__ float scratch[24576];  // 96 KiB: [0,1024) used, rest pins 1 wg/CU

  const int wg = blockIdx.x;
  const int bblk = wg & 3;          // batch group (16 rows)
  const int cb = wg >> 2;           // 0..63
  const bool zwg = (cb >= 32);
  const int tid = threadIdx.x;
  const int lane = tid & 63;
  const int wv = tid >> 6;
  const int kgrp = lane >> 4;
  const int c = lane & 15;

  const int P1C0 = cb * 16;                   // phase-1 col base in [0,1024)
  const int P2C0 = zwg ? (cb - 32) * 16 : 0;  // phase-2 u col base

  u32* h2 = (u32*)(ws + H2_OFF);    // [buf][row][k]
  u32* hr2 = (u32*)(ws + HR2_OFF);  // [buf][row][k]

  // ---- one-time: weight B-fragments -> registers (bf16 hi/lo split, RNE).
  bf16x8 w1hi[6], w1lo[6], w2hi[6], w2lo[6];
#pragma unroll
  for (int j = 0; j < 6; ++j) {
    const int kb = (wv + 4 * j) * 32 + kgrp * 8;
#pragma unroll
    for (int i = 0; i < 8; ++i) {
      const int k = kb + i;
      float v = (k < DD) ? Wk[(size_t)k * 1024 + P1C0 + c]
                         : Wrk[(size_t)(k - DD) * 1024 + P1C0 + c];
      unsigned short hb = f2bf(v);
      w1hi[j][i] = (short)hb;
      w1lo[j][i] = (short)f2bf(v - bf2f(hb));
      float v2 = 0.f;
      if (zwg)
        v2 = (k < DD) ? Wu[(size_t)k * UU + P2C0 + c]
                      : Wur[(size_t)(k - DD) * UU + P2C0 + c];
      unsigned short hb2 = f2bf(v2);
      w2hi[j][i] = (short)hb2;
      w2lo[j][i] = (short)f2bf(v2 - bf2f(hb2));
    }
  }

  const int bl = tid >> 4, cl = tid & 15;  // reduce-thread coords
  const int Bg = bblk * 16 + bl;
  const float b1 = brk[P1C0 + cl];
  const float b2 = zwg ? bur[P2C0 + cl] : 0.f;

  const int rowb = bblk * 16 + c;  // A-operand batch row for this lane

  // x fragments for the current step (shared by phase-1 and xu GEMMs).
  bf16x8 xhi[2], xlo[2];
  auto split_x = [&](int t) {
#pragma unroll
    for (int j = 0; j < 2; ++j) {
      const float* xr =
          x + ((size_t)rowb * TT + t) * DD + wv * 32 + j * 128 + kgrp * 8;
      f32x4 v0 = *(const f32x4*)(xr);
      f32x4 v1 = *(const f32x4*)(xr + 4);
#pragma unroll
      for (int i = 0; i < 4; ++i) {
        unsigned short hb = f2bf(v0[i]);
        xhi[j][i] = (short)hb;
        xlo[j][i] = (short)f2bf(v0[i] - bf2f(hb));
        unsigned short hb2 = f2bf(v1[i]);
        xhi[j][4 + i] = (short)hb2;
        xlo[j][4 + i] = (short)f2bf(v1[i] - bf2f(hb2));
      }
    }
  };

  // Poll one 8-element chunk of tagged u32 until tags match, then unpack to
  // bf16 hi(trunc)/lo fragments. Wave-uniform loop (__all).
  auto poll_chunk = [&](const u32* p, u32 exp, bf16x8& AHI, bf16x8& ALO) {
    u32 q[8];
    for (;;) {
      q[0] = ld_coh_u32(p + 0); q[1] = ld_coh_u32(p + 1);
      q[2] = ld_coh_u32(p + 2); q[3] = ld_coh_u32(p + 3);
      q[4] = ld_coh_u32(p + 4); q[5] = ld_coh_u32(p + 5);
      q[6] = ld_coh_u32(p + 6); q[7] = ld_coh_u32(p + 7);
      int ok = ((q[0] & TAGM) == exp) & ((q[1] & TAGM) == exp) &
               ((q[2] & TAGM) == exp) & ((q[3] & TAGM) == exp) &
               ((q[4] & TAGM) == exp) & ((q[5] & TAGM) == exp) &
               ((q[6] & TAGM) == exp) & ((q[7] & TAGM) == exp);
      if (__all(ok)) break;
      __builtin_amdgcn_s_sleep(1);
    }
#pragma unroll
    for (int i = 0; i < 8; ++i) {
      u32 v = q[i] & 0xFFFFF800u;            // drop tag
      AHI[i] = (short)(v >> 16);             // truncated bf16 hi
      float f = __builtin_bit_cast(float, v);
      float fl = f - __builtin_bit_cast(float, v & 0xFFFF0000u);
      ALO[i] = (short)f2bf(fl);              // lo remainder
    }
  };

  split_x(0);

  for (int t = 0; t < TT; ++t) {
    const u32 texp = (u32)t & TAGM;          // tag of h(t-1)
    const u32 tstore = (u32)(t + 1) & TAGM;  // tag for h(t) and hr(t)
    const u32* hrow = h2 + ((size_t)(((t + 1) & 1) * 64) + rowb) * 512;

    // ================= phase 1: z/r = [x|h(t-1)] @ [Wk;Wrk] + brk (all wgs)
    f32x4 a0 = {0.f, 0.f, 0.f, 0.f}, a1 = {0.f, 0.f, 0.f, 0.f};
    a0 = MFMA(xhi[0], w1hi[0], a0);
    a0 = MFMA(xhi[0], w1lo[0], a0);
    a0 = MFMA(xlo[0], w1hi[0], a0);
    a1 = MFMA(xhi[1], w1hi[1], a1);
    a1 = MFMA(xhi[1], w1lo[1], a1);
    a1 = MFMA(xlo[1], w1hi[1], a1);
#pragma unroll
    for (int j = 2; j < 6; ++j) {
      const int kh = 32 * (wv + 4 * j - 8) + kgrp * 8;
      bf16x8 ahi, alo;
      poll_chunk(hrow + kh, texp, ahi, alo);
      if ((j & 1) == 0) {
        a0 = MFMA(ahi, w1hi[j], a0);
        a0 = MFMA(ahi, w1lo[j], a0);
        a0 = MFMA(alo, w1hi[j], a0);
      } else {
        a1 = MFMA(ahi, w1hi[j], a1);
        a1 = MFMA(ahi, w1lo[j], a1);
        a1 = MFMA(alo, w1hi[j], a1);
      }
    }
    {
      f32x4 acc = a0 + a1;
#pragma unroll
      for (int r = 0; r < 4; ++r)
        scratch[wv * 256 + (kgrp * 4 + r) * 16 + c] = acc[r];
    }
    __syncthreads();
    const float zsum = (scratch[tid] + scratch[256 + tid]) +
                       (scratch[512 + tid] + scratch[768 + tid]) + b1;
    const float s = 1.f / (1.f + __expf(-zsum));

    if (!zwg) {
      // r gate -> hr = h*r. Own h element already confirmed visible (this
      // wg's 4 waves polled all 16 rows x all k, then __syncthreads).
      u32 hp = ld_coh_u32(h2 + ((size_t)(((t + 1) & 1) * 64) + Bg) * 512 +
                          P1C0 + cl);
      float hrv = untag(hp) * s;
      u32 hv = (__builtin_bit_cast(u32, hrv) & 0xFFFFF800u) | tstore;
      st_coh_u32(hr2 + ((size_t)((t & 1) * 64) + Bg) * 512 + P1C0 + cl, hv);
      if (t + 1 < TT) split_x(t + 1);
      // next-step scratch WAR: transitively ordered through hr->h->poll chain
    } else {
      const float zt = s;  // update gate stays in register
      // xu partial (x-only chunks of u-GEMM) — hr-independent, do it now.
      f32x4 u0 = {0.f, 0.f, 0.f, 0.f}, u1 = {0.f, 0.f, 0.f, 0.f};
      u0 = MFMA(xhi[0], w2hi[0], u0);
      u0 = MFMA(xhi[0], w2lo[0], u0);
      u0 = MFMA(xlo[0], w2hi[0], u0);
      u1 = MFMA(xhi[1], w2hi[1], u1);
      u1 = MFMA(xhi[1], w2lo[1], u1);
      u1 = MFMA(xlo[1], w2hi[1], u1);
      __syncthreads();  // scratch WAR: phase-1 reads done before phase-2 write
      if (t + 1 < TT) split_x(t + 1);  // x(t+1) loads hide under hr poll

      // ================= phase 2: u h-part = hr(t) @ Wur
      const u32* hrrow = hr2 + ((size_t)((t & 1) * 64) + rowb) * 512;
#pragma unroll
      for (int j = 2; j < 6; ++j) {
        const int kh = 32 * (wv + 4 * j - 8) + kgrp * 8;
        bf16x8 ahi, alo;
        poll_chunk(hrrow + kh, tstore, ahi, alo);
        if ((j & 1) == 0) {
          u0 = MFMA(ahi, w2hi[j], u0);
          u0 = MFMA(ahi, w2lo[j], u0);
          u0 = MFMA(alo, w2hi[j], u0);
        } else {
          u1 = MFMA(ahi, w2hi[j], u1);
          u1 = MFMA(ahi, w2lo[j], u1);
          u1 = MFMA(alo, w2hi[j], u1);
        }
      }
      {
        f32x4 acc = u0 + u1;
#pragma unroll
        for (int r = 0; r < 4; ++r)
          scratch[wv * 256 + (kgrp * 4 + r) * 16 + c] = acc[r];
      }
      __syncthreads();
      const float usum = (scratch[tid] + scratch[256 + tid]) +
                         (scratch[512 + tid] + scratch[768 + tid]) + b2;
      __syncthreads();  // scratch WAR: phase-2 reads done before next write
      const float e = __expf(2.f * usum);
      const float ht = 1.f - 2.f / (e + 1.f);  // tanh(usum)
      u32 hp2 = ld_coh_u32(h2 + ((size_t)(((t + 1) & 1) * 64) + Bg) * 512 +
                           P2C0 + cl);
      float ho = untag(hp2);
      float hn = ho + zt * (ht - ho);
      u32 hv = (__builtin_bit_cast(u32, hn) & 0xFFFFF800u) | tstore;
      st_coh_u32(h2 + ((size_t)((t & 1) * 64) + Bg) * 512 + P2C0 + cl, hv);
      if (t == TT - 1) out[(size_t)Bg * UU + P2C0 + cl] = hn;
    }
  }
}

extern "C" void kernel_launch(void* const* d_in, const int* in_sizes, int n_in,
                              void* d_out, int out_size, void* d_ws,
                              size_t ws_size, hipStream_t stream) {
  (void)in_sizes; (void)n_in; (void)out_size; (void)ws_size;
  hipMemsetAsync(d_ws, 0, WS_BYTES, stream);  // h(-1)=0 with tag 0 == ready@t=0
  gru_persist<<<dim3(256), dim3(256), 0, stream>>>(
      (const float*)d_in[0], (const float*)d_in[1], (const float*)d_in[2],
      (const float*)d_in[3], (const float*)d_in[4], (const float*)d_in[5],
      (const float*)d_in[6], (float*)d_out, (unsigned char*)d_ws);
}